// Round 2
// baseline (310.782 us; speedup 1.0000x reference)
//
#include <hip/hip_runtime.h>

// Fused Conv3d(3->16, 3x3x3, VALID) + bias + channel softmax + maxpool(4,4,4)/4.
// x: [512,3,16,32,32] f32, w: [16,3,3,3,3] f32, b: [16] f32
// out: [512,16,3,7,7] f32
//
// Grid: one block per (n, pd, ph) = 512*3*7 = 10752 blocks, 128 threads.
// Each thread computes one (h,w) conv column for 4 d-positions x 16 channels
// in registers, then softmax per d, then pooled max via LDS atomics.
// Only conv positions inside pooled windows are computed (d<12, h,w<28).

#define XS_ROW 33  // 32 + 1 pad to break LDS bank stride

__global__ __launch_bounds__(128) void conv_sm_pool(
    const float* __restrict__ x, const float* __restrict__ w,
    const float* __restrict__ b, float* __restrict__ out) {
  __shared__ float xs[3 * 6 * 6 * XS_ROW];          // [cin][ld][lh][lw]
  __shared__ __align__(16) float wl[81 * 16];       // [tap][c], tap=cin*27+kd*9+kh*3+kw
  __shared__ float pool[7 * 16];                    // [pw][c]

  const int tid = threadIdx.x;
  const int blk = blockIdx.x;
  const int n  = blk / 21;
  const int r  = blk % 21;
  const int pd = r / 7;
  const int ph = r % 7;

  // ---- stage input tile: cin 0..2, d 4pd..4pd+5, h 4ph..4ph+5, w 0..31 ----
  const float* xb = x + ((size_t)n * 3 * 16 * 32 * 32)
                      + (size_t)(4 * pd) * 32 * 32 + (size_t)(4 * ph) * 32;
  for (int i = tid; i < 3 * 6 * 6 * 32; i += 128) {
    int lw = i & 31;
    int rest = i >> 5;           // cin*36 + ld*6 + lh
    int lh = rest % 6;
    int rest2 = rest / 6;
    int ld = rest2 % 6;
    int cin = rest2 / 6;
    xs[((cin * 6 + ld) * 6 + lh) * XS_ROW + lw] =
        xb[((cin * 16 + ld) * 32 + lh) * 32 + lw];
  }
  // ---- stage weights transposed to [tap][c] ----
  for (int i = tid; i < 81 * 16; i += 128) {
    int c = i & 15, t = i >> 4;
    wl[i] = w[c * 81 + t];
  }
  if (tid < 112) pool[tid] = 0.0f;  // softmax probs are > 0
  __syncthreads();

  if (tid < 112) {
    const int dh = tid / 28;     // 0..3  (conv h = 4*ph + dh)
    const int wp = tid % 28;     // 0..27 (conv w)

    float acc[4][16];
#pragma unroll
    for (int c = 0; c < 16; ++c) {
      float bc = b[c];           // uniform -> scalar load
#pragma unroll
      for (int dd = 0; dd < 4; ++dd) acc[dd][c] = bc;
    }

    const float4* w4 = reinterpret_cast<const float4*>(wl);
    // constant-bound nested loops: all LDS offsets fold to immediates
    for (int cin = 0; cin < 3; ++cin) {
      for (int kh = 0; kh < 3; ++kh) {
#pragma unroll
        for (int kw = 0; kw < 3; ++kw) {
          float in[6];
#pragma unroll
          for (int ld = 0; ld < 6; ++ld)
            in[ld] = xs[((cin * 6 + ld) * 6 + (dh + kh)) * XS_ROW + (wp + kw)];
#pragma unroll
          for (int kr = 0; kr < 3; ++kr) {     // kd
            const int t = cin * 27 + kr * 9 + kh * 3 + kw;
#pragma unroll
            for (int j = 0; j < 4; ++j) {
              float4 wv = w4[t * 4 + j];       // broadcast read, 4 channels
#pragma unroll
              for (int dd = 0; dd < 4; ++dd) {
                acc[dd][j * 4 + 0] = fmaf(in[dd + kr], wv.x, acc[dd][j * 4 + 0]);
                acc[dd][j * 4 + 1] = fmaf(in[dd + kr], wv.y, acc[dd][j * 4 + 1]);
                acc[dd][j * 4 + 2] = fmaf(in[dd + kr], wv.z, acc[dd][j * 4 + 2]);
                acc[dd][j * 4 + 3] = fmaf(in[dd + kr], wv.w, acc[dd][j * 4 + 3]);
              }
            }
          }
        }
      }
    }

    // ---- softmax over 16 channels per dd, then max over dd ----
    float pm[16];
#pragma unroll
    for (int c = 0; c < 16; ++c) pm[c] = 0.0f;
#pragma unroll
    for (int dd = 0; dd < 4; ++dd) {
      float m = acc[dd][0];
#pragma unroll
      for (int c = 1; c < 16; ++c) m = fmaxf(m, acc[dd][c]);
      float s = 0.0f;
#pragma unroll
      for (int c = 0; c < 16; ++c) {
        acc[dd][c] = __expf(acc[dd][c] - m);
        s += acc[dd][c];
      }
      float rs = 1.0f / s;
#pragma unroll
      for (int c = 0; c < 16; ++c) pm[c] = fmaxf(pm[c], acc[dd][c] * rs);
    }

    // ---- pooled max over the 4x4 (h,w) window via LDS atomics ----
    const int pw = wp >> 2;
#pragma unroll
    for (int c = 0; c < 16; ++c)
      atomicMax(reinterpret_cast<int*>(&pool[pw * 16 + c]),
                __float_as_int(pm[c]));  // probs > 0: int order == float order
  }
  __syncthreads();

  if (tid < 112) {
    int c = tid / 7, pw = tid % 7;
    out[(((size_t)n * 16 + c) * 3 + pd) * 49 + (size_t)ph * 7 + pw] =
        pool[pw * 16 + c];
  }
}

extern "C" void kernel_launch(void* const* d_in, const int* in_sizes, int n_in,
                              void* d_out, int out_size, void* d_ws, size_t ws_size,
                              hipStream_t stream) {
  const float* x = (const float*)d_in[0];
  const float* w = (const float*)d_in[1];
  const float* b = (const float*)d_in[2];
  float* out = (float*)d_out;
  (void)in_sizes; (void)n_in; (void)out_size; (void)d_ws; (void)ws_size;
  dim3 grid(512 * 3 * 7);
  dim3 block(128);
  hipLaunchKernelGGL(conv_sm_pool, grid, block, 0, stream, x, w, b, out);
}